// Round 7
// baseline (259.270 us; speedup 1.0000x reference)
//
#include <hip/hip_runtime.h>
#include <stdint.h>

// MultiHeadAttention: B=2, S=2048, HIDDEN=1024, NH=16, HD=64, causal.
// R7: kill the scratch bug. R5/R6's kva[cur][j] (runtime cur) forced the
//     "register prefetch" into scratch = global memory (attn WRITE_SIZE was
//     262 MB vs 8 MB of real output). K-loop now unrolled by 2 with
//     statically-named prefetch registers (k0a/v0a, k1a/v1a) -> true VGPR
//     prefetch. Everything else identical to R6: Q-tile 64, K-tile 64,
//     double-buffered LDS, 1 barrier/step, longest-first dispatch, exp2 math
//     (Q pre-scaled log2e/8), truncating P store, l via MFMA-ones.
// MFMA 16x16x32 bf16 layouts (HW-verified):
//   A/B frag: lane holds row[m=lane&15][k=(lane>>4)*8 + j]
//   C/D:      row=(lane>>4)*4+reg, col=lane&15

#define HIDDEN 1024
#define NH 16
#define HD 64
#define BATCH 2
#define SEQ 2048

typedef unsigned short u16;
typedef unsigned int u32;
typedef __attribute__((ext_vector_type(8))) short short8;   // 8 bf16
typedef __attribute__((ext_vector_type(4))) float f32x4;

__device__ __forceinline__ u16 f2bf(float f) {
    u32 u = __float_as_uint(f);
    return (u16)((u + 0x7FFFu + ((u >> 16) & 1u)) >> 16);   // RNE
}

// ---------------- fused fp32 -> bf16 conversion (x + 4 weights) -----------
__global__ void cvt_all(const float* __restrict__ x, const float* __restrict__ Wq,
                        const float* __restrict__ Wk, const float* __restrict__ Wv,
                        const float* __restrict__ Wo, u16* __restrict__ xb,
                        u16* __restrict__ wqb, u16* __restrict__ wkb,
                        u16* __restrict__ wvb, u16* __restrict__ wob) {
    const int blk = blockIdx.x;
    const float* src; u16* dst; int base;
    if (blk < 2048)      { src = x;  dst = xb;  base = blk; }
    else if (blk < 2560) { src = Wq; dst = wqb; base = blk - 2048; }
    else if (blk < 3072) { src = Wk; dst = wkb; base = blk - 2560; }
    else if (blk < 3584) { src = Wv; dst = wvb; base = blk - 3072; }
    else                 { src = Wo; dst = wob; base = blk - 3584; }
    const int i = base * 256 + threadIdx.x;
    float4 a = ((const float4*)src)[2 * i];
    float4 b = ((const float4*)src)[2 * i + 1];
    union { u16 h[8]; uint4 v; } o;
    o.h[0] = f2bf(a.x); o.h[1] = f2bf(a.y); o.h[2] = f2bf(a.z); o.h[3] = f2bf(a.w);
    o.h[4] = f2bf(b.x); o.h[5] = f2bf(b.y); o.h[6] = f2bf(b.z); o.h[7] = f2bf(b.w);
    ((uint4*)dst)[i] = o.v;
}

// ---------------- shared GEMM K-loop (128x128 tile, BK=32) ----------------
#define GEMM_LDA 40
__device__ __forceinline__ void gemm_kloop(const u16* __restrict__ A,
                                           const u16* __restrict__ Wt,
                                           u16* As, u16* Bs, f32x4 (*acc)[4],
                                           int m0, int n0, int t) {
    const int lane = t & 63;
    const int w = t >> 6;
    const int quad = lane >> 4;
    const int lm = lane & 15;
    const int wm = (w & 1) * 64;
    const int wn = (w >> 1) * 64;
    const int srow = t >> 2;
    const int schunk = (t & 3) * 8;
    for (int k0 = 0; k0 < 1024; k0 += 32) {
        uint4 a0 = *(const uint4*)(A + (size_t)(m0 + srow) * 1024 + k0 + schunk);
        uint4 a1 = *(const uint4*)(A + (size_t)(m0 + srow + 64) * 1024 + k0 + schunk);
        uint4 b0 = *(const uint4*)(Wt + (size_t)(n0 + srow) * 1024 + k0 + schunk);
        uint4 b1 = *(const uint4*)(Wt + (size_t)(n0 + srow + 64) * 1024 + k0 + schunk);
        __syncthreads();
        *(uint4*)(As + srow * GEMM_LDA + schunk) = a0;
        *(uint4*)(As + (srow + 64) * GEMM_LDA + schunk) = a1;
        *(uint4*)(Bs + srow * GEMM_LDA + schunk) = b0;
        *(uint4*)(Bs + (srow + 64) * GEMM_LDA + schunk) = b1;
        __syncthreads();
        short8 af[4], bf[4];
#pragma unroll
        for (int mi = 0; mi < 4; mi++)
            af[mi] = *(const short8*)(As + (wm + mi * 16 + lm) * GEMM_LDA + quad * 8);
#pragma unroll
        for (int ni = 0; ni < 4; ni++)
            bf[ni] = *(const short8*)(Bs + (wn + ni * 16 + lm) * GEMM_LDA + quad * 8);
#pragma unroll
        for (int mi = 0; mi < 4; mi++)
#pragma unroll
            for (int ni = 0; ni < 4; ni++)
                acc[mi][ni] = __builtin_amdgcn_mfma_f32_16x16x32_bf16(
                    af[mi], bf[ni], acc[mi][ni], 0, 0, 0);
    }
}

// ---------------- fused QKV projection ------------------------------------
__launch_bounds__(256, 2)
__global__ void gemm_qkv(const u16* __restrict__ A, const u16* __restrict__ Wqb,
                         const u16* __restrict__ Wkb, const u16* __restrict__ Wvb,
                         const float* __restrict__ bq, const float* __restrict__ bk,
                         const float* __restrict__ bv, u16* __restrict__ Qo,
                         u16* __restrict__ Ko, u16* __restrict__ Vo) {
    __shared__ u16 As[128 * GEMM_LDA];
    __shared__ u16 Bs[128 * GEMM_LDA];
    const int which = blockIdx.x >> 3;
    const int n0 = (blockIdx.x & 7) * 128;
    const int m0 = blockIdx.y * 128;
    const u16* Wt = (which == 0) ? Wqb : (which == 1) ? Wkb : Wvb;
    const float* bias = (which == 0) ? bq : (which == 1) ? bk : bv;
    u16* out = (which == 0) ? Qo : (which == 1) ? Ko : Vo;
    const float oscale = (which == 0) ? 0.18033688011112042f : 1.0f;  // log2e/8
    const int t = threadIdx.x;
    const int lane = t & 63, w = t >> 6, quad = lane >> 4, lm = lane & 15;
    const int wm = (w & 1) * 64, wn = (w >> 1) * 64;

    f32x4 acc[4][4] = {};
    gemm_kloop(A, Wt, As, Bs, acc, m0, n0, t);

#pragma unroll
    for (int ni = 0; ni < 4; ni++) {
        const int n = n0 + wn + ni * 16 + lm;
        const float bv_ = bias[n];
        const int h = n >> 6, d = n & 63;
#pragma unroll
        for (int mi = 0; mi < 4; mi++)
#pragma unroll
            for (int r = 0; r < 4; r++) {
                const int m = m0 + wm + mi * 16 + quad * 4 + r;
                const int b = m >> 11, s = m & 2047;
                const u16 hv = f2bf((acc[mi][ni][r] + bv_) * oscale);
                if (which == 2)
                    out[(((size_t)(b * NH + h) * HD + d) * SEQ) + s] = hv;
                else
                    out[(((size_t)(b * NH + h) * SEQ + s) * HD) + d] = hv;
            }
    }
}

// ---------------- output projection (fp32 out + bias) ---------------------
__launch_bounds__(256, 2)
__global__ void gemm_out(const u16* __restrict__ A, const u16* __restrict__ Wt,
                         const float* __restrict__ bias, float* __restrict__ out) {
    __shared__ u16 As[128 * GEMM_LDA];
    __shared__ u16 Bs[128 * GEMM_LDA];
    const int n0 = blockIdx.x * 128;
    const int m0 = blockIdx.y * 128;
    const int t = threadIdx.x;
    const int lane = t & 63, w = t >> 6, quad = lane >> 4, lm = lane & 15;
    const int wm = (w & 1) * 64, wn = (w >> 1) * 64;

    f32x4 acc[4][4] = {};
    gemm_kloop(A, Wt, As, Bs, acc, m0, n0, t);

#pragma unroll
    for (int ni = 0; ni < 4; ni++) {
        const int n = n0 + wn + ni * 16 + lm;
        const float bv_ = bias[n];
#pragma unroll
        for (int mi = 0; mi < 4; mi++)
#pragma unroll
            for (int r = 0; r < 4; r++) {
                const int m = m0 + wm + mi * 16 + quad * 4 + r;
                out[(size_t)m * 1024 + n] = acc[mi][ni][r] + bv_;
            }
    }
}

// ---------------- flash attention, causal, pipelined ----------------------
// Grid 1024 blocks (longest-first), 256 thr = 4 waves; wave owns 16 q-rows;
// Q-tile 64, K-tile 64, double-buffered LDS, depth-2 STATIC-register
// prefetch (loop unrolled x2 so all prefetch regs have static names).
__launch_bounds__(256, 3)
__global__ void attn_kernel(const u16* __restrict__ Q, const u16* __restrict__ K,
                            const u16* __restrict__ Vt, u16* __restrict__ Out) {
    constexpr int LDK = 72;   // 64 + 8
    constexpr int LDV = 72;   // 64 + 8
    constexpr int LDP = 68;   // 64 + 4
    __shared__ u16 Ks[2][64 * LDK];   // 18432 B
    __shared__ u16 Vs[2][64 * LDV];   // 18432 B
    __shared__ u16 Ps[4 * 16 * LDP];  //  8704 B  -> total 45568 B
    const int t = threadIdx.x;
    const int lane = t & 63, w = t >> 6, quad = lane >> 4, lm = lane & 15;
    const int qt = 31 - (blockIdx.x >> 5);   // longest-first
    const int bh = blockIdx.x & 31;
    const int b = bh >> 4, h = bh & 15;
    const size_t base = (size_t)(b * NH + h) * SEQ * HD;
    const u16* Qg = Q + base;
    const u16* Kg = K + base;
    const u16* Vg = Vt + base;
    const int q0 = qt * 64 + w * 16;
    const int nk = qt + 1;   // number of 64-key steps

    short8 qf[2];
#pragma unroll
    for (int kk = 0; kk < 2; kk++)
        qf[kk] = *(const short8*)(Qg + (size_t)(q0 + lm) * HD + kk * 32 + quad * 8);

    f32x4 oacc[4] = {};
    f32x4 lacc = {};
    short8 ones;
#pragma unroll
    for (int j = 0; j < 8; j++) ones[j] = (short)0x3F80;   // bf16 1.0

    u16* Pw = Ps + w * 16 * LDP;
    const int srow0 = t >> 3, schunk = (t & 7) * 8;   // rows srow0, srow0+32

    // one fused step: QK^T -> mask -> exp2 -> P(LDS) -> PV + l
    auto compute_step = [&](const u16* Kc, const u16* Vc, int kt_) {
        f32x4 sacc[4];
#pragma unroll
        for (int n = 0; n < 4; n++) {
            short8 kf0 = *(const short8*)(Kc + (n * 16 + lm) * LDK + quad * 8);
            short8 kf1 = *(const short8*)(Kc + (n * 16 + lm) * LDK + 32 + quad * 8);
            f32x4 a = {};
            a = __builtin_amdgcn_mfma_f32_16x16x32_bf16(qf[0], kf0, a, 0, 0, 0);
            a = __builtin_amdgcn_mfma_f32_16x16x32_bf16(qf[1], kf1, a, 0, 0, 0);
            sacc[n] = a;
        }
        if (kt_ == qt) {   // causal mask, diagonal tile only
#pragma unroll
            for (int n = 0; n < 4; n++)
#pragma unroll
                for (int r = 0; r < 4; r++)
                    if (n * 16 + lm > w * 16 + quad * 4 + r)
                        sacc[n][r] = -__builtin_inff();
        }
#pragma unroll
        for (int n = 0; n < 4; n++)
#pragma unroll
            for (int r = 0; r < 4; r++)
                Pw[(quad * 4 + r) * LDP + n * 16 + lm] =
                    (u16)(__float_as_uint(exp2f(sacc[n][r])) >> 16);
        short8 pf[2];
#pragma unroll
        for (int k4 = 0; k4 < 2; k4++)
            pf[k4] = *(const short8*)(Pw + lm * LDP + k4 * 32 + quad * 8);
#pragma unroll
        for (int n = 0; n < 4; n++)
#pragma unroll
            for (int k4 = 0; k4 < 2; k4++) {
                short8 vf = *(const short8*)(Vc + (n * 16 + lm) * LDV + k4 * 32 + quad * 8);
                oacc[n] = __builtin_amdgcn_mfma_f32_16x16x32_bf16(pf[k4], vf, oacc[n], 0, 0, 0);
            }
#pragma unroll
        for (int k4 = 0; k4 < 2; k4++)
            lacc = __builtin_amdgcn_mfma_f32_16x16x32_bf16(pf[k4], ones, lacc, 0, 0, 0);
    };

    // ---- depth-2 prefetch with STATIC register names ----
    uint4 k0a[2], v0a[2], k1a[2], v1a[2];
#pragma unroll
    for (int j = 0; j < 2; j++) {       // tile 0 -> k0a/v0a
        const int row = srow0 + j * 32;
        k0a[j] = *(const uint4*)(Kg + (size_t)(0 * 64 + row) * HD + schunk);
        v0a[j] = *(const uint4*)(Vg + (size_t)row * SEQ + 0 * 64 + schunk);
    }
    {
        const int kt1 = (nk > 1) ? 1 : 0;  // tile 1 -> k1a/v1a
#pragma unroll
        for (int j = 0; j < 2; j++) {
            const int row = srow0 + j * 32;
            k1a[j] = *(const uint4*)(Kg + (size_t)(kt1 * 64 + row) * HD + schunk);
            v1a[j] = *(const uint4*)(Vg + (size_t)row * SEQ + kt1 * 64 + schunk);
        }
    }
#pragma unroll
    for (int j = 0; j < 2; j++) {       // store tile 0 -> buf 0
        const int row = srow0 + j * 32;
        *(uint4*)(&Ks[0][row * LDK + schunk]) = k0a[j];
        *(uint4*)(&Vs[0][row * LDV + schunk]) = v0a[j];
    }

    for (int kt = 0; kt < nk; kt += 2) {
        // ---- even step: consume buf0 ----
        __syncthreads();                 // buf0 stores visible
        if (kt + 2 < nk) {               // prefetch tile kt+2 -> k0a/v0a
#pragma unroll
            for (int j = 0; j < 2; j++) {
                const int row = srow0 + j * 32;
                k0a[j] = *(const uint4*)(Kg + (size_t)((kt + 2) * 64 + row) * HD + schunk);
                v0a[j] = *(const uint4*)(Vg + (size_t)row * SEQ + (kt + 2) * 64 + schunk);
            }
        }
        if (kt + 1 < nk) {               // store tile kt+1 -> buf1 (overlaps compute)
#pragma unroll
            for (int j = 0; j < 2; j++) {
                const int row = srow0 + j * 32;
                *(uint4*)(&Ks[1][row * LDK + schunk]) = k1a[j];
                *(uint4*)(&Vs[1][row * LDV + schunk]) = v1a[j];
            }
        }
        compute_step(Ks[0], Vs[0], kt);
        if (kt + 1 >= nk) break;

        // ---- odd step: consume buf1 ----
        __syncthreads();                 // buf1 stores visible
        if (kt + 3 < nk) {               // prefetch tile kt+3 -> k1a/v1a
#pragma unroll
            for (int j = 0; j < 2; j++) {
                const int row = srow0 + j * 32;
                k1a[j] = *(const uint4*)(Kg + (size_t)((kt + 3) * 64 + row) * HD + schunk);
                v1a[j] = *(const uint4*)(Vg + (size_t)row * SEQ + (kt + 3) * 64 + schunk);
            }
        }
        if (kt + 2 < nk) {               // store tile kt+2 -> buf0
#pragma unroll
            for (int j = 0; j < 2; j++) {
                const int row = srow0 + j * 32;
                *(uint4*)(&Ks[0][row * LDK + schunk]) = k0a[j];
                *(uint4*)(&Vs[0][row * LDV + schunk]) = v0a[j];
            }
        }
        compute_step(Ks[1], Vs[1], kt + 1);
    }

    // epilogue
    float inv[4];
#pragma unroll
    for (int r = 0; r < 4; r++) inv[r] = 1.0f / lacc[r];
#pragma unroll
    for (int n = 0; n < 4; n++)
#pragma unroll
        for (int r = 0; r < 4; r++) {
            const int qq = q0 + quad * 4 + r;
            Out[(size_t)(b * SEQ + qq) * HIDDEN + h * HD + n * 16 + lm] =
                f2bf(oacc[n][r] * inv[r]);
        }
}

// ---------------- launcher ------------------------------------------------
extern "C" void kernel_launch(void* const* d_in, const int* in_sizes, int n_in,
                              void* d_out, int out_size, void* d_ws, size_t ws_size,
                              hipStream_t stream) {
    const float* x  = (const float*)d_in[0];
    const float* Wq = (const float*)d_in[1];
    const float* bq = (const float*)d_in[2];
    const float* Wk = (const float*)d_in[3];
    const float* bk = (const float*)d_in[4];
    const float* Wv = (const float*)d_in[5];
    const float* bv = (const float*)d_in[6];
    const float* Wo = (const float*)d_in[7];
    const float* bo = (const float*)d_in[8];
    float* out = (float*)d_out;

    char* ws = (char*)d_ws;
    const size_t SZ_X = (size_t)4096 * 1024 * 2;   // 8 MB bf16
    const size_t SZ_W = (size_t)1024 * 1024 * 2;   // 2 MB bf16
    u16* xb    = (u16*)(ws);
    u16* wqb   = (u16*)(ws + SZ_X);
    u16* wkb   = (u16*)(ws + SZ_X + SZ_W);
    u16* wvb   = (u16*)(ws + SZ_X + 2 * SZ_W);
    u16* wob   = (u16*)(ws + SZ_X + 3 * SZ_W);
    u16* Qb    = (u16*)(ws + SZ_X + 4 * SZ_W);
    u16* Kb    = (u16*)(ws + 2 * SZ_X + 4 * SZ_W);
    u16* Vtb   = (u16*)(ws + 3 * SZ_X + 4 * SZ_W);
    u16* attnb = (u16*)(ws + 4 * SZ_X + 4 * SZ_W);

    cvt_all<<<4096, 256, 0, stream>>>(x, Wq, Wk, Wv, Wo, xb, wqb, wkb, wvb, wob);
    gemm_qkv<<<dim3(24, 32), 256, 0, stream>>>(xb, wqb, wkb, wvb, bq, bk, bv, Qb, Kb, Vtb);
    attn_kernel<<<BATCH * NH * (SEQ / 64), 256, 0, stream>>>(Qb, Kb, Vtb, attnb);
    gemm_out<<<dim3(8, 32), 256, 0, stream>>>(attnb, wob, bo, out);
}

// Round 8
// 204.502 us; speedup vs baseline: 1.2678x; 1.2678x over previous
//
#include <hip/hip_runtime.h>
#include <stdint.h>

// MultiHeadAttention: B=2, S=2048, HIDDEN=1024, NH=16, HD=64, causal.
// R8: attn staging via __builtin_amdgcn_global_load_lds (async global->LDS,
//     NO prefetch VGPRs -> nothing for the compiler to spill; R5-R7 all spilled
//     the register pipeline to scratch: WRITE_SIZE 262/161 MB vs 8 MB real).
//     global_load_lds requires unpadded lane-contiguous LDS, so bank conflicts
//     are handled with an XOR chunk swizzle: slot c of row r holds chunk
//     c^(r&7) (16B chunks). Frag reads then hit all 32 banks 2-way (free).
//     Pipeline: issue tile kt+1 -> compute tile kt -> __syncthreads (vmcnt
//     drain lands the async loads). One barrier/step. Keeps: Q-tile 64,
//     K-tile 64, longest-first dispatch, exp2 math (Q pre-scaled log2e/8),
//     truncating P store, l via MFMA-ones.
// MFMA 16x16x32 bf16 layouts (HW-verified):
//   A/B frag: lane holds row[m=lane&15][k=(lane>>4)*8 + j]
//   C/D:      row=(lane>>4)*4+reg, col=lane&15

#define HIDDEN 1024
#define NH 16
#define HD 64
#define BATCH 2
#define SEQ 2048

typedef unsigned short u16;
typedef unsigned int u32;
typedef __attribute__((ext_vector_type(8))) short short8;   // 8 bf16
typedef __attribute__((ext_vector_type(4))) float f32x4;

typedef const __attribute__((address_space(1))) u32 gu32;
typedef __attribute__((address_space(3))) u32 lu32;

__device__ __forceinline__ u16 f2bf(float f) {
    u32 u = __float_as_uint(f);
    return (u16)((u + 0x7FFFu + ((u >> 16) & 1u)) >> 16);   // RNE
}

// ---------------- fused fp32 -> bf16 conversion (x + 4 weights) -----------
__global__ void cvt_all(const float* __restrict__ x, const float* __restrict__ Wq,
                        const float* __restrict__ Wk, const float* __restrict__ Wv,
                        const float* __restrict__ Wo, u16* __restrict__ xb,
                        u16* __restrict__ wqb, u16* __restrict__ wkb,
                        u16* __restrict__ wvb, u16* __restrict__ wob) {
    const int blk = blockIdx.x;
    const float* src; u16* dst; int base;
    if (blk < 2048)      { src = x;  dst = xb;  base = blk; }
    else if (blk < 2560) { src = Wq; dst = wqb; base = blk - 2048; }
    else if (blk < 3072) { src = Wk; dst = wkb; base = blk - 2560; }
    else if (blk < 3584) { src = Wv; dst = wvb; base = blk - 3072; }
    else                 { src = Wo; dst = wob; base = blk - 3584; }
    const int i = base * 256 + threadIdx.x;
    float4 a = ((const float4*)src)[2 * i];
    float4 b = ((const float4*)src)[2 * i + 1];
    union { u16 h[8]; uint4 v; } o;
    o.h[0] = f2bf(a.x); o.h[1] = f2bf(a.y); o.h[2] = f2bf(a.z); o.h[3] = f2bf(a.w);
    o.h[4] = f2bf(b.x); o.h[5] = f2bf(b.y); o.h[6] = f2bf(b.z); o.h[7] = f2bf(b.w);
    ((uint4*)dst)[i] = o.v;
}

// ---------------- shared GEMM K-loop (128x128 tile, BK=32) ----------------
#define GEMM_LDA 40
__device__ __forceinline__ void gemm_kloop(const u16* __restrict__ A,
                                           const u16* __restrict__ Wt,
                                           u16* As, u16* Bs, f32x4 (*acc)[4],
                                           int m0, int n0, int t) {
    const int lane = t & 63;
    const int w = t >> 6;
    const int quad = lane >> 4;
    const int lm = lane & 15;
    const int wm = (w & 1) * 64;
    const int wn = (w >> 1) * 64;
    const int srow = t >> 2;
    const int schunk = (t & 3) * 8;
    for (int k0 = 0; k0 < 1024; k0 += 32) {
        uint4 a0 = *(const uint4*)(A + (size_t)(m0 + srow) * 1024 + k0 + schunk);
        uint4 a1 = *(const uint4*)(A + (size_t)(m0 + srow + 64) * 1024 + k0 + schunk);
        uint4 b0 = *(const uint4*)(Wt + (size_t)(n0 + srow) * 1024 + k0 + schunk);
        uint4 b1 = *(const uint4*)(Wt + (size_t)(n0 + srow + 64) * 1024 + k0 + schunk);
        __syncthreads();
        *(uint4*)(As + srow * GEMM_LDA + schunk) = a0;
        *(uint4*)(As + (srow + 64) * GEMM_LDA + schunk) = a1;
        *(uint4*)(Bs + srow * GEMM_LDA + schunk) = b0;
        *(uint4*)(Bs + (srow + 64) * GEMM_LDA + schunk) = b1;
        __syncthreads();
        short8 af[4], bf[4];
#pragma unroll
        for (int mi = 0; mi < 4; mi++)
            af[mi] = *(const short8*)(As + (wm + mi * 16 + lm) * GEMM_LDA + quad * 8);
#pragma unroll
        for (int ni = 0; ni < 4; ni++)
            bf[ni] = *(const short8*)(Bs + (wn + ni * 16 + lm) * GEMM_LDA + quad * 8);
#pragma unroll
        for (int mi = 0; mi < 4; mi++)
#pragma unroll
            for (int ni = 0; ni < 4; ni++)
                acc[mi][ni] = __builtin_amdgcn_mfma_f32_16x16x32_bf16(
                    af[mi], bf[ni], acc[mi][ni], 0, 0, 0);
    }
}

// ---------------- fused QKV projection ------------------------------------
__launch_bounds__(256, 2)
__global__ void gemm_qkv(const u16* __restrict__ A, const u16* __restrict__ Wqb,
                         const u16* __restrict__ Wkb, const u16* __restrict__ Wvb,
                         const float* __restrict__ bq, const float* __restrict__ bk,
                         const float* __restrict__ bv, u16* __restrict__ Qo,
                         u16* __restrict__ Ko, u16* __restrict__ Vo) {
    __shared__ u16 As[128 * GEMM_LDA];
    __shared__ u16 Bs[128 * GEMM_LDA];
    const int which = blockIdx.x >> 3;
    const int n0 = (blockIdx.x & 7) * 128;
    const int m0 = blockIdx.y * 128;
    const u16* Wt = (which == 0) ? Wqb : (which == 1) ? Wkb : Wvb;
    const float* bias = (which == 0) ? bq : (which == 1) ? bk : bv;
    u16* out = (which == 0) ? Qo : (which == 1) ? Ko : Vo;
    const float oscale = (which == 0) ? 0.18033688011112042f : 1.0f;  // log2e/8
    const int t = threadIdx.x;
    const int lane = t & 63, w = t >> 6, quad = lane >> 4, lm = lane & 15;
    const int wm = (w & 1) * 64, wn = (w >> 1) * 64;

    f32x4 acc[4][4] = {};
    gemm_kloop(A, Wt, As, Bs, acc, m0, n0, t);

#pragma unroll
    for (int ni = 0; ni < 4; ni++) {
        const int n = n0 + wn + ni * 16 + lm;
        const float bv_ = bias[n];
        const int h = n >> 6, d = n & 63;
#pragma unroll
        for (int mi = 0; mi < 4; mi++)
#pragma unroll
            for (int r = 0; r < 4; r++) {
                const int m = m0 + wm + mi * 16 + quad * 4 + r;
                const int b = m >> 11, s = m & 2047;
                const u16 hv = f2bf((acc[mi][ni][r] + bv_) * oscale);
                if (which == 2)
                    out[(((size_t)(b * NH + h) * HD + d) * SEQ) + s] = hv;
                else
                    out[(((size_t)(b * NH + h) * SEQ + s) * HD) + d] = hv;
            }
    }
}

// ---------------- output projection (fp32 out + bias) ---------------------
__launch_bounds__(256, 2)
__global__ void gemm_out(const u16* __restrict__ A, const u16* __restrict__ Wt,
                         const float* __restrict__ bias, float* __restrict__ out) {
    __shared__ u16 As[128 * GEMM_LDA];
    __shared__ u16 Bs[128 * GEMM_LDA];
    const int n0 = blockIdx.x * 128;
    const int m0 = blockIdx.y * 128;
    const int t = threadIdx.x;
    const int lane = t & 63, w = t >> 6, quad = lane >> 4, lm = lane & 15;
    const int wm = (w & 1) * 64, wn = (w >> 1) * 64;

    f32x4 acc[4][4] = {};
    gemm_kloop(A, Wt, As, Bs, acc, m0, n0, t);

#pragma unroll
    for (int ni = 0; ni < 4; ni++) {
        const int n = n0 + wn + ni * 16 + lm;
        const float bv_ = bias[n];
#pragma unroll
        for (int mi = 0; mi < 4; mi++)
#pragma unroll
            for (int r = 0; r < 4; r++) {
                const int m = m0 + wm + mi * 16 + quad * 4 + r;
                out[(size_t)m * 1024 + n] = acc[mi][ni][r] + bv_;
            }
    }
}

// ---------------- flash attention, causal, async-staged -------------------
// Grid 1024 blocks (longest-first), 256 thr = 4 waves; wave owns 16 q-rows;
// Q-tile 64, K-tile 64, double-buffered LDS via global_load_lds, XOR-swizzled
// chunks (no padding). One barrier/step.
__launch_bounds__(256, 3)
__global__ void attn_kernel(const u16* __restrict__ Q, const u16* __restrict__ K,
                            const u16* __restrict__ Vt, u16* __restrict__ Out) {
    constexpr int LDP = 68;           // Ps keeps padded layout (VALU-written)
    __shared__ u16 Ks[2][64 * 64];    // 2 x 8 KB, swizzled
    __shared__ u16 Vs[2][64 * 64];    // 2 x 8 KB, swizzled
    __shared__ u16 Ps[4 * 16 * LDP];  // 8704 B   -> total 41472 B
    const int t = threadIdx.x;
    const int lane = t & 63, w = t >> 6, quad = lane >> 4, lm = lane & 15;
    const int qt = 31 - (blockIdx.x >> 5);   // longest-first
    const int bh = blockIdx.x & 31;
    const int b = bh >> 4, h = bh & 15;
    const size_t base = (size_t)(b * NH + h) * SEQ * HD;
    const u16* Qg = Q + base;
    const u16* Kg = K + base;
    const u16* Vg = Vt + base;
    const int q0 = qt * 64 + w * 16;
    const int nk = qt + 1;   // number of 64-key steps

    short8 qf[2];
#pragma unroll
    for (int kk = 0; kk < 2; kk++)
        qf[kk] = *(const short8*)(Qg + (size_t)(q0 + lm) * HD + kk * 32 + quad * 8);

    f32x4 oacc[4] = {};
    f32x4 lacc = {};
    short8 ones;
#pragma unroll
    for (int j = 0; j < 8; j++) ones[j] = (short)0x3F80;   // bf16 1.0

    u16* Pw = Ps + w * 16 * LDP;

    // async staging: wave w covers rows w*16..w*16+15 of both K and V^T tiles.
    // lane l -> row w*16 + j*8 + (l>>3), physical chunk slot l&7; slot c of
    // row r holds logical chunk c^(r&7). HW writes lane l at ldsbase + l*16B.
    const int srow = (lane >> 3);          // 0..7 within 8-row group
    const int schunk = (lane & 7) ^ srow;  // source logical chunk (r&7 == srow)
    auto stage_kv = [&](int kt, int buf) {
#pragma unroll
        for (int j = 0; j < 2; j++) {
            const int row = w * 16 + j * 8 + srow;
            const u16* gk = Kg + (size_t)(kt * 64 + row) * HD + schunk * 8;
            const u16* gv = Vg + (size_t)row * SEQ + kt * 64 + schunk * 8;
            __builtin_amdgcn_global_load_lds((gu32*)gk, (lu32*)(&Ks[buf][(w * 16 + j * 8) * 64]), 16, 0, 0);
            __builtin_amdgcn_global_load_lds((gu32*)gv, (lu32*)(&Vs[buf][(w * 16 + j * 8) * 64]), 16, 0, 0);
        }
    };

    // one fused step: QK^T -> mask -> exp2 -> P(LDS) -> PV + l
    auto compute_step = [&](const u16* Kc, const u16* Vc, int kt_) {
        f32x4 sacc[4];
#pragma unroll
        for (int n = 0; n < 4; n++) {
            const int r = n * 16 + lm;
            const u16* rowp = Kc + r * 64;
            short8 kf0 = *(const short8*)(rowp + ((quad ^ (r & 7)) * 8));
            short8 kf1 = *(const short8*)(rowp + (((quad + 4) ^ (r & 7)) * 8));
            f32x4 a = {};
            a = __builtin_amdgcn_mfma_f32_16x16x32_bf16(qf[0], kf0, a, 0, 0, 0);
            a = __builtin_amdgcn_mfma_f32_16x16x32_bf16(qf[1], kf1, a, 0, 0, 0);
            sacc[n] = a;
        }
        if (kt_ == qt) {   // causal mask, diagonal tile only
#pragma unroll
            for (int n = 0; n < 4; n++)
#pragma unroll
                for (int r = 0; r < 4; r++)
                    if (n * 16 + lm > w * 16 + quad * 4 + r)
                        sacc[n][r] = -__builtin_inff();
        }
#pragma unroll
        for (int n = 0; n < 4; n++)
#pragma unroll
            for (int r = 0; r < 4; r++)
                Pw[(quad * 4 + r) * LDP + n * 16 + lm] =
                    (u16)(__float_as_uint(exp2f(sacc[n][r])) >> 16);
        short8 pf[2];
#pragma unroll
        for (int k4 = 0; k4 < 2; k4++)
            pf[k4] = *(const short8*)(Pw + lm * LDP + k4 * 32 + quad * 8);
#pragma unroll
        for (int n = 0; n < 4; n++) {
            const int r = n * 16 + lm;
            const u16* rowp = Vc + r * 64;
#pragma unroll
            for (int k4 = 0; k4 < 2; k4++) {
                short8 vf = *(const short8*)(rowp + (((k4 * 4 + quad) ^ (r & 7)) * 8));
                oacc[n] = __builtin_amdgcn_mfma_f32_16x16x32_bf16(pf[k4], vf, oacc[n], 0, 0, 0);
            }
        }
#pragma unroll
        for (int k4 = 0; k4 < 2; k4++)
            lacc = __builtin_amdgcn_mfma_f32_16x16x32_bf16(pf[k4], ones, lacc, 0, 0, 0);
    };

    // preamble: stage tile 0 -> buf0; barrier drains the async loads
    stage_kv(0, 0);
    __syncthreads();

    for (int kt = 0; kt < nk; kt++) {
        const int cur = kt & 1;
        if (kt + 1 < nk) stage_kv(kt + 1, cur ^ 1);   // async, no VGPRs held
        compute_step(Ks[cur], Vs[cur], kt);
        __syncthreads();   // drains vmcnt (tile kt+1 landed) + guards buf reuse
    }

    // epilogue
    float inv[4];
#pragma unroll
    for (int r = 0; r < 4; r++) inv[r] = 1.0f / lacc[r];
#pragma unroll
    for (int n = 0; n < 4; n++)
#pragma unroll
        for (int r = 0; r < 4; r++) {
            const int qq = q0 + quad * 4 + r;
            Out[(size_t)(b * SEQ + qq) * HIDDEN + h * HD + n * 16 + lm] =
                f2bf(oacc[n][r] * inv[r]);
        }
}

// ---------------- launcher ------------------------------------------------
extern "C" void kernel_launch(void* const* d_in, const int* in_sizes, int n_in,
                              void* d_out, int out_size, void* d_ws, size_t ws_size,
                              hipStream_t stream) {
    const float* x  = (const float*)d_in[0];
    const float* Wq = (const float*)d_in[1];
    const float* bq = (const float*)d_in[2];
    const float* Wk = (const float*)d_in[3];
    const float* bk = (const float*)d_in[4];
    const float* Wv = (const float*)d_in[5];
    const float* bv = (const float*)d_in[6];
    const float* Wo = (const float*)d_in[7];
    const float* bo = (const float*)d_in[8];
    float* out = (float*)d_out;

    char* ws = (char*)d_ws;
    const size_t SZ_X = (size_t)4096 * 1024 * 2;   // 8 MB bf16
    const size_t SZ_W = (size_t)1024 * 1024 * 2;   // 2 MB bf16
    u16* xb    = (u16*)(ws);
    u16* wqb   = (u16*)(ws + SZ_X);
    u16* wkb   = (u16*)(ws + SZ_X + SZ_W);
    u16* wvb   = (u16*)(ws + SZ_X + 2 * SZ_W);
    u16* wob   = (u16*)(ws + SZ_X + 3 * SZ_W);
    u16* Qb    = (u16*)(ws + SZ_X + 4 * SZ_W);
    u16* Kb    = (u16*)(ws + 2 * SZ_X + 4 * SZ_W);
    u16* Vtb   = (u16*)(ws + 3 * SZ_X + 4 * SZ_W);
    u16* attnb = (u16*)(ws + 4 * SZ_X + 4 * SZ_W);

    cvt_all<<<4096, 256, 0, stream>>>(x, Wq, Wk, Wv, Wo, xb, wqb, wkb, wvb, wob);
    gemm_qkv<<<dim3(24, 32), 256, 0, stream>>>(xb, wqb, wkb, wvb, bq, bk, bv, Qb, Kb, Vtb);
    attn_kernel<<<BATCH * NH * (SEQ / 64), 256, 0, stream>>>(Qb, Kb, Vtb, attnb);
    gemm_out<<<dim3(8, 32), 256, 0, stream>>>(attnb, wob, bo, out);
}

// Round 10
// 200.623 us; speedup vs baseline: 1.2923x; 1.0193x over previous
//
#include <hip/hip_runtime.h>
#include <stdint.h>

// MultiHeadAttention: B=2, S=2048, HIDDEN=1024, NH=16, HD=64, causal.
// R10: fix R9's launcher/kernel mismatch — gemm_out was retiled to 64-row
//      blocks but still launched with 32 y-blocks, leaving rows 2048..4095
//      unwritten (absmax 1.16 = second batch element all zeros). Launch is
//      now dim3(8, 64). All kernel code identical to R9:
//      async global_load_lds staging + XOR swizzle + dbuf in both GEMMs,
//      R8 attn (57us, 0 conflicts), fused cvt.
// MFMA 16x16x32 bf16 layouts (HW-verified):
//   A/B frag: lane holds row[m=lane&15][k=(lane>>4)*8 + j]
//   C/D:      row=(lane>>4)*4+reg, col=lane&15
// Swizzle (R8-proven): row of 64B = 4 slots of 16B; phys slot c holds logical
//   chunk c^(r&3). 8-lane LDS phases hit distinct banks (2-way max = free).

#define HIDDEN 1024
#define NH 16
#define HD 64
#define BATCH 2
#define SEQ 2048

typedef unsigned short u16;
typedef unsigned int u32;
typedef __attribute__((ext_vector_type(8))) short short8;   // 8 bf16
typedef __attribute__((ext_vector_type(4))) float f32x4;

typedef const __attribute__((address_space(1))) u32 gu32;
typedef __attribute__((address_space(3))) u32 lu32;

__device__ __forceinline__ u16 f2bf(float f) {
    u32 u = __float_as_uint(f);
    return (u16)((u + 0x7FFFu + ((u >> 16) & 1u)) >> 16);   // RNE
}

// ---------------- fused fp32 -> bf16 conversion (x + 4 weights) -----------
__global__ void cvt_all(const float* __restrict__ x, const float* __restrict__ Wq,
                        const float* __restrict__ Wk, const float* __restrict__ Wv,
                        const float* __restrict__ Wo, u16* __restrict__ xb,
                        u16* __restrict__ wqb, u16* __restrict__ wkb,
                        u16* __restrict__ wvb, u16* __restrict__ wob) {
    const int blk = blockIdx.x;
    const float* src; u16* dst; int base;
    if (blk < 2048)      { src = x;  dst = xb;  base = blk; }
    else if (blk < 2560) { src = Wq; dst = wqb; base = blk - 2048; }
    else if (blk < 3072) { src = Wk; dst = wkb; base = blk - 2560; }
    else if (blk < 3584) { src = Wv; dst = wvb; base = blk - 3072; }
    else                 { src = Wo; dst = wob; base = blk - 3584; }
    const int i = base * 256 + threadIdx.x;
    float4 a = ((const float4*)src)[2 * i];
    float4 b = ((const float4*)src)[2 * i + 1];
    union { u16 h[8]; uint4 v; } o;
    o.h[0] = f2bf(a.x); o.h[1] = f2bf(a.y); o.h[2] = f2bf(a.z); o.h[3] = f2bf(a.w);
    o.h[4] = f2bf(b.x); o.h[5] = f2bf(b.y); o.h[6] = f2bf(b.z); o.h[7] = f2bf(b.w);
    ((uint4*)dst)[i] = o.v;
}

// ---- async stage: 16 rows x 32 cols (64 B/row) per call, XOR-4 swizzle ----
// lane l -> row rbase + (l>>2), phys slot l&3, sourcing logical chunk
// (l&3)^((l>>2)&3). HW writes lane l at ldsbase + l*16B.
__device__ __forceinline__ void stage16(const u16* __restrict__ G, int grow0,
                                        int k0, u16* lds, int rbase, int lane) {
    const int sr = lane >> 2;
    const int lc = (lane & 3) ^ (sr & 3);
    const u16* g = G + (size_t)(grow0 + rbase + sr) * 1024 + k0 + lc * 8;
    __builtin_amdgcn_global_load_lds((gu32*)g, (lu32*)(lds + rbase * 32), 16, 0, 0);
}

// ---------------- fused QKV projection ------------------------------------
// grid (24, 32): blockIdx.x>>3 selects {Q,K,V}; Q/K -> [B,H,S,D], V -> [B,H,D,S].
// 128x128 tile, BK=32, async dbuf staging, one barrier/iter. 768 blocks = 3/CU.
__launch_bounds__(256, 3)
__global__ void gemm_qkv(const u16* __restrict__ A, const u16* __restrict__ Wqb,
                         const u16* __restrict__ Wkb, const u16* __restrict__ Wvb,
                         const float* __restrict__ bq, const float* __restrict__ bk,
                         const float* __restrict__ bv, u16* __restrict__ Qo,
                         u16* __restrict__ Ko, u16* __restrict__ Vo) {
    __shared__ u16 As[2][128 * 32];   // 2 x 8 KB
    __shared__ u16 Bs[2][128 * 32];   // 2 x 8 KB -> 32 KB total
    const int which = blockIdx.x >> 3;
    const int n0 = (blockIdx.x & 7) * 128;
    const int m0 = blockIdx.y * 128;
    const u16* Wt = (which == 0) ? Wqb : (which == 1) ? Wkb : Wvb;
    const float* bias = (which == 0) ? bq : (which == 1) ? bk : bv;
    u16* out = (which == 0) ? Qo : (which == 1) ? Ko : Vo;
    const float oscale = (which == 0) ? 0.18033688011112042f : 1.0f;  // log2e/8
    const int t = threadIdx.x;
    const int lane = t & 63, w = t >> 6, quad = lane >> 4, lm = lane & 15;
    const int wm = (w & 1) * 64, wn = (w >> 1) * 64;

    f32x4 acc[4][4] = {};

    auto stage = [&](int k0, int buf) {
        stage16(A, m0, k0, As[buf], w * 32, lane);
        stage16(A, m0, k0, As[buf], w * 32 + 16, lane);
        stage16(Wt, n0, k0, Bs[buf], w * 32, lane);
        stage16(Wt, n0, k0, Bs[buf], w * 32 + 16, lane);
    };

    stage(0, 0);
    __syncthreads();
    for (int k0 = 0; k0 < 1024; k0 += 32) {
        const int cur = (k0 >> 5) & 1;
        if (k0 + 32 < 1024) stage(k0 + 32, cur ^ 1);
        short8 af[4], bf[4];
        const int sw = (quad ^ (lm & 3)) * 8;   // swizzled slot offset (elems)
#pragma unroll
        for (int mi = 0; mi < 4; mi++)
            af[mi] = *(const short8*)(&As[cur][(wm + mi * 16 + lm) * 32] + sw);
#pragma unroll
        for (int ni = 0; ni < 4; ni++)
            bf[ni] = *(const short8*)(&Bs[cur][(wn + ni * 16 + lm) * 32] + sw);
#pragma unroll
        for (int mi = 0; mi < 4; mi++)
#pragma unroll
            for (int ni = 0; ni < 4; ni++)
                acc[mi][ni] = __builtin_amdgcn_mfma_f32_16x16x32_bf16(
                    af[mi], bf[ni], acc[mi][ni], 0, 0, 0);
        __syncthreads();   // drains vmcnt (next tile landed) + guards buf reuse
    }

#pragma unroll
    for (int ni = 0; ni < 4; ni++) {
        const int n = n0 + wn + ni * 16 + lm;
        const float bv_ = bias[n];
        const int h = n >> 6, d = n & 63;
#pragma unroll
        for (int mi = 0; mi < 4; mi++)
#pragma unroll
            for (int r = 0; r < 4; r++) {
                const int m = m0 + wm + mi * 16 + quad * 4 + r;
                const int b = m >> 11, s = m & 2047;
                const u16 hv = f2bf((acc[mi][ni][r] + bv_) * oscale);
                if (which == 2)
                    out[(((size_t)(b * NH + h) * HD + d) * SEQ) + s] = hv;
                else
                    out[(((size_t)(b * NH + h) * SEQ + s) * HD) + d] = hv;
            }
    }
}

// ---------------- output projection (fp32 out + bias) ---------------------
// 64x128 tile (wave = 32x64), grid (8,64) = 512 blocks = 2/CU, async dbuf.
__launch_bounds__(256, 2)
__global__ void gemm_out(const u16* __restrict__ A, const u16* __restrict__ Wt,
                         const float* __restrict__ bias, float* __restrict__ out) {
    __shared__ u16 As[2][64 * 32];    // 2 x 4 KB
    __shared__ u16 Bs[2][128 * 32];   // 2 x 8 KB -> 24 KB total
    const int n0 = blockIdx.x * 128;
    const int m0 = blockIdx.y * 64;
    const int t = threadIdx.x;
    const int lane = t & 63, w = t >> 6, quad = lane >> 4, lm = lane & 15;
    const int wm = (w & 1) * 32, wn = (w >> 1) * 64;

    f32x4 acc[2][4] = {};

    auto stage = [&](int k0, int buf) {
        stage16(A, m0, k0, As[buf], w * 16, lane);
        stage16(Wt, n0, k0, Bs[buf], w * 32, lane);
        stage16(Wt, n0, k0, Bs[buf], w * 32 + 16, lane);
    };

    stage(0, 0);
    __syncthreads();
    for (int k0 = 0; k0 < 1024; k0 += 32) {
        const int cur = (k0 >> 5) & 1;
        if (k0 + 32 < 1024) stage(k0 + 32, cur ^ 1);
        short8 af[2], bf[4];
        const int sw = (quad ^ (lm & 3)) * 8;
#pragma unroll
        for (int mi = 0; mi < 2; mi++)
            af[mi] = *(const short8*)(&As[cur][(wm + mi * 16 + lm) * 32] + sw);
#pragma unroll
        for (int ni = 0; ni < 4; ni++)
            bf[ni] = *(const short8*)(&Bs[cur][(wn + ni * 16 + lm) * 32] + sw);
#pragma unroll
        for (int mi = 0; mi < 2; mi++)
#pragma unroll
            for (int ni = 0; ni < 4; ni++)
                acc[mi][ni] = __builtin_amdgcn_mfma_f32_16x16x32_bf16(
                    af[mi], bf[ni], acc[mi][ni], 0, 0, 0);
        __syncthreads();
    }

#pragma unroll
    for (int ni = 0; ni < 4; ni++) {
        const int n = n0 + wn + ni * 16 + lm;
        const float bv_ = bias[n];
#pragma unroll
        for (int mi = 0; mi < 2; mi++)
#pragma unroll
            for (int r = 0; r < 4; r++) {
                const int m = m0 + wm + mi * 16 + quad * 4 + r;
                out[(size_t)m * 1024 + n] = acc[mi][ni][r] + bv_;
            }
    }
}

// ---------------- flash attention, causal, async-staged (R8, unchanged) ---
__launch_bounds__(256, 3)
__global__ void attn_kernel(const u16* __restrict__ Q, const u16* __restrict__ K,
                            const u16* __restrict__ Vt, u16* __restrict__ Out) {
    constexpr int LDP = 68;           // Ps keeps padded layout (VALU-written)
    __shared__ u16 Ks[2][64 * 64];    // 2 x 8 KB, swizzled
    __shared__ u16 Vs[2][64 * 64];    // 2 x 8 KB, swizzled
    __shared__ u16 Ps[4 * 16 * LDP];  // 8704 B   -> total 41472 B
    const int t = threadIdx.x;
    const int lane = t & 63, w = t >> 6, quad = lane >> 4, lm = lane & 15;
    const int qt = 31 - (blockIdx.x >> 5);   // longest-first
    const int bh = blockIdx.x & 31;
    const int b = bh >> 4, h = bh & 15;
    const size_t base = (size_t)(b * NH + h) * SEQ * HD;
    const u16* Qg = Q + base;
    const u16* Kg = K + base;
    const u16* Vg = Vt + base;
    const int q0 = qt * 64 + w * 16;
    const int nk = qt + 1;   // number of 64-key steps

    short8 qf[2];
#pragma unroll
    for (int kk = 0; kk < 2; kk++)
        qf[kk] = *(const short8*)(Qg + (size_t)(q0 + lm) * HD + kk * 32 + quad * 8);

    f32x4 oacc[4] = {};
    f32x4 lacc = {};
    short8 ones;
#pragma unroll
    for (int j = 0; j < 8; j++) ones[j] = (short)0x3F80;   // bf16 1.0

    u16* Pw = Ps + w * 16 * LDP;

    const int srow = (lane >> 3);          // 0..7 within 8-row group
    const int schunk = (lane & 7) ^ srow;  // source logical chunk (r&7 == srow)
    auto stage_kv = [&](int kt, int buf) {
#pragma unroll
        for (int j = 0; j < 2; j++) {
            const int row = w * 16 + j * 8 + srow;
            const u16* gk = Kg + (size_t)(kt * 64 + row) * HD + schunk * 8;
            const u16* gv = Vg + (size_t)row * SEQ + kt * 64 + schunk * 8;
            __builtin_amdgcn_global_load_lds((gu32*)gk, (lu32*)(&Ks[buf][(w * 16 + j * 8) * 64]), 16, 0, 0);
            __builtin_amdgcn_global_load_lds((gu32*)gv, (lu32*)(&Vs[buf][(w * 16 + j * 8) * 64]), 16, 0, 0);
        }
    };

    auto compute_step = [&](const u16* Kc, const u16* Vc, int kt_) {
        f32x4 sacc[4];
#pragma unroll
        for (int n = 0; n < 4; n++) {
            const int r = n * 16 + lm;
            const u16* rowp = Kc + r * 64;
            short8 kf0 = *(const short8*)(rowp + ((quad ^ (r & 7)) * 8));
            short8 kf1 = *(const short8*)(rowp + (((quad + 4) ^ (r & 7)) * 8));
            f32x4 a = {};
            a = __builtin_amdgcn_mfma_f32_16x16x32_bf16(qf[0], kf0, a, 0, 0, 0);
            a = __builtin_amdgcn_mfma_f32_16x16x32_bf16(qf[1], kf1, a, 0, 0, 0);
            sacc[n] = a;
        }
        if (kt_ == qt) {   // causal mask, diagonal tile only
#pragma unroll
            for (int n = 0; n < 4; n++)
#pragma unroll
                for (int r = 0; r < 4; r++)
                    if (n * 16 + lm > w * 16 + quad * 4 + r)
                        sacc[n][r] = -__builtin_inff();
        }
#pragma unroll
        for (int n = 0; n < 4; n++)
#pragma unroll
            for (int r = 0; r < 4; r++)
                Pw[(quad * 4 + r) * LDP + n * 16 + lm] =
                    (u16)(__float_as_uint(exp2f(sacc[n][r])) >> 16);
        short8 pf[2];
#pragma unroll
        for (int k4 = 0; k4 < 2; k4++)
            pf[k4] = *(const short8*)(Pw + lm * LDP + k4 * 32 + quad * 8);
#pragma unroll
        for (int n = 0; n < 4; n++) {
            const int r = n * 16 + lm;
            const u16* rowp = Vc + r * 64;
#pragma unroll
            for (int k4 = 0; k4 < 2; k4++) {
                short8 vf = *(const short8*)(rowp + (((k4 * 4 + quad) ^ (r & 7)) * 8));
                oacc[n] = __builtin_amdgcn_mfma_f32_16x16x32_bf16(pf[k4], vf, oacc[n], 0, 0, 0);
            }
        }
#pragma unroll
        for (int k4 = 0; k4 < 2; k4++)
            lacc = __builtin_amdgcn_mfma_f32_16x16x32_bf16(pf[k4], ones, lacc, 0, 0, 0);
    };

    stage_kv(0, 0);
    __syncthreads();

    for (int kt = 0; kt < nk; kt++) {
        const int cur = kt & 1;
        if (kt + 1 < nk) stage_kv(kt + 1, cur ^ 1);   // async, no VGPRs held
        compute_step(Ks[cur], Vs[cur], kt);
        __syncthreads();   // drains vmcnt (tile kt+1 landed) + guards buf reuse
    }

    float inv[4];
#pragma unroll
    for (int r = 0; r < 4; r++) inv[r] = 1.0f / lacc[r];
#pragma unroll
    for (int n = 0; n < 4; n++)
#pragma unroll
        for (int r = 0; r < 4; r++) {
            const int qq = q0 + quad * 4 + r;
            Out[(size_t)(b * SEQ + qq) * HIDDEN + h * HD + n * 16 + lm] =
                f2bf(oacc[n][r] * inv[r]);
        }
}

// ---------------- launcher ------------------------------------------------
extern "C" void kernel_launch(void* const* d_in, const int* in_sizes, int n_in,
                              void* d_out, int out_size, void* d_ws, size_t ws_size,
                              hipStream_t stream) {
    const float* x  = (const float*)d_in[0];
    const float* Wq = (const float*)d_in[1];
    const float* bq = (const float*)d_in[2];
    const float* Wk = (const float*)d_in[3];
    const float* bk = (const float*)d_in[4];
    const float* Wv = (const float*)d_in[5];
    const float* bv = (const float*)d_in[6];
    const float* Wo = (const float*)d_in[7];
    const float* bo = (const float*)d_in[8];
    float* out = (float*)d_out;

    char* ws = (char*)d_ws;
    const size_t SZ_X = (size_t)4096 * 1024 * 2;   // 8 MB bf16
    const size_t SZ_W = (size_t)1024 * 1024 * 2;   // 2 MB bf16
    u16* xb    = (u16*)(ws);
    u16* wqb   = (u16*)(ws + SZ_X);
    u16* wkb   = (u16*)(ws + SZ_X + SZ_W);
    u16* wvb   = (u16*)(ws + SZ_X + 2 * SZ_W);
    u16* wob   = (u16*)(ws + SZ_X + 3 * SZ_W);
    u16* Qb    = (u16*)(ws + SZ_X + 4 * SZ_W);
    u16* Kb    = (u16*)(ws + 2 * SZ_X + 4 * SZ_W);
    u16* Vtb   = (u16*)(ws + 3 * SZ_X + 4 * SZ_W);
    u16* attnb = (u16*)(ws + 4 * SZ_X + 4 * SZ_W);

    cvt_all<<<4096, 256, 0, stream>>>(x, Wq, Wk, Wv, Wo, xb, wqb, wkb, wvb, wob);
    gemm_qkv<<<dim3(24, 32), 256, 0, stream>>>(xb, wqb, wkb, wvb, bq, bk, bv, Qb, Kb, Vtb);
    attn_kernel<<<BATCH * NH * (SEQ / 64), 256, 0, stream>>>(Qb, Kb, Vtb, attnb);
    gemm_out<<<dim3(8, 64), 256, 0, stream>>>(attnb, wob, bo, out);  // 64-row tiles!
}